// Round 1
// baseline (1525.454 us; speedup 1.0000x reference)
//
#include <hip/hip_runtime.h>

typedef unsigned short u16;
typedef unsigned int u32;

#define NSB 250  // scan blocks

__device__ __forceinline__ float bf2f(u16 h) {
    return __uint_as_float(((u32)h) << 16);
}
__device__ __forceinline__ u16 f2bf(float f) {
    u32 u = __float_as_uint(f);
    u += 0x7fffu + ((u >> 16) & 1u);   // round-to-nearest-even
    return (u16)(u >> 16);
}

// ---------------- degree histogram ----------------
__global__ void k_degrees(const int* __restrict__ src, const int* __restrict__ dst,
                          int* __restrict__ outdeg, int* __restrict__ indeg, int E) {
    int stride = gridDim.x * blockDim.x;
    for (int e = blockIdx.x * blockDim.x + threadIdx.x; e < E; e += stride) {
        atomicAdd(&outdeg[src[e]], 1);
        atomicAdd(&indeg[dst[e]], 1);
    }
}

__global__ void k_norms(const int* __restrict__ outdeg, const int* __restrict__ indeg,
                        float* __restrict__ onorm, float* __restrict__ inorm, int N) {
    int i = blockIdx.x * blockDim.x + threadIdx.x;
    if (i < N) {
        int od = outdeg[i]; if (od < 1) od = 1;
        int id = indeg[i];  if (id < 1) id = 1;
        onorm[i] = 1.0f / sqrtf((float)od);
        inorm[i] = 1.0f / sqrtf((float)id);
    }
}

// ---------------- exclusive scan of indeg -> row_ptr ----------------
__global__ __launch_bounds__(256) void k_scan_partial(const int* __restrict__ indeg,
                                                      int* __restrict__ bsum, int N, int CH) {
    __shared__ int sh[256];
    int b = blockIdx.x, t = threadIdx.x;
    long base = (long)b * CH;
    int s = 0;
    for (int i = t; i < CH; i += 256) {
        long g = base + i;
        if (g < N) s += indeg[g];
    }
    sh[t] = s; __syncthreads();
    for (int off = 128; off > 0; off >>= 1) {
        if (t < off) sh[t] += sh[t + off];
        __syncthreads();
    }
    if (t == 0) bsum[b] = sh[0];
}

__global__ __launch_bounds__(256) void k_scan_top(const int* __restrict__ bsum,
                                                  int* __restrict__ bsex, int* __restrict__ rp, int N) {
    __shared__ int sh[256];
    int t = threadIdx.x;
    int v = (t < NSB) ? bsum[t] : 0;
    sh[t] = v; __syncthreads();
    for (int off = 1; off < 256; off <<= 1) {
        int x = (t >= off) ? sh[t - off] : 0;
        __syncthreads();
        sh[t] += x;
        __syncthreads();
    }
    bsex[t] = sh[t] - v;              // exclusive
    if (t == NSB - 1) rp[N] = sh[t];  // total = E
}

__global__ __launch_bounds__(256) void k_scan_write(const int* __restrict__ indeg,
                                                    const int* __restrict__ bsex,
                                                    int* __restrict__ rp, int N, int CH) {
    extern __shared__ int shc[];
    int b = blockIdx.x, t = threadIdx.x;
    long base = (long)b * CH;
    for (int i = t; i < CH; i += 256) shc[i] = (base + i < N) ? indeg[base + i] : 0;
    __syncthreads();
    if (t == 0) {
        int run = bsex[b];
        for (int i = 0; i < CH; ++i) { int x = shc[i]; shc[i] = run; run += x; }
    }
    __syncthreads();
    for (int i = t; i < CH; i += 256) if (base + i < N) rp[base + i] = shc[i];
}

// ---------------- CSR fill (dst-sorted src ids) ----------------
__global__ void k_fill(const int* __restrict__ src, const int* __restrict__ dst,
                       const int* __restrict__ rp, int* __restrict__ cursor,
                       int* __restrict__ es, int E) {
    int stride = gridDim.x * blockDim.x;
    for (int e = blockIdx.x * blockDim.x + threadIdx.x; e < E; e += stride) {
        int d = dst[e];
        int p = atomicAdd(&cursor[d], 1);
        es[rp[d] + p] = src[e];
    }
}

// ---------------- fp32 GEMM, row-scaled epilogue, bf16 out ----------------
// out[n][c] = bf16( rscale[n] * sum_k in[n][k] * W[k][c] ),  K = 256 fixed.
template <int COLS, bool IN_BF16>
__global__ __launch_bounds__(256) void k_gemm_scale(const void* __restrict__ inp,
                                                    const float* __restrict__ W,
                                                    const float* __restrict__ rscale,
                                                    u16* __restrict__ outp, int nrows) {
    const int K = 256, KC = 32;
    __shared__ float sX[KC][64];   // [k][m]
    __shared__ float sW[KC][64];   // [k][n]
    int t = threadIdx.x;
    int tx = t & 15, ty = t >> 4;
    int row0 = blockIdx.x * 64;
    int col0 = blockIdx.y * 64;
    float acc[4][4] = {};

    int sr  = t >> 2;          // 0..63 staged row
    int skq = (t & 3) * 8;     // staged k offset (8 per thread)
    int swk = t >> 3;          // 0..31 staged W k
    int swn = (t & 7) * 8;     // staged W col offset

    int gr_s = row0 + sr; if (gr_s >= nrows) gr_s = nrows - 1;

    for (int kc = 0; kc < K; kc += KC) {
        if (!IN_BF16) {
            const float* xp = (const float*)inp + (size_t)gr_s * K + kc + skq;
            float4 a = *(const float4*)xp;
            float4 b = *(const float4*)(xp + 4);
            sX[skq + 0][sr] = a.x; sX[skq + 1][sr] = a.y; sX[skq + 2][sr] = a.z; sX[skq + 3][sr] = a.w;
            sX[skq + 4][sr] = b.x; sX[skq + 5][sr] = b.y; sX[skq + 6][sr] = b.z; sX[skq + 7][sr] = b.w;
        } else {
            const u16* xp = (const u16*)inp + (size_t)gr_s * K + kc + skq;
            uint4 u = *(const uint4*)xp;
            sX[skq + 0][sr] = bf2f((u16)(u.x & 0xffffu)); sX[skq + 1][sr] = bf2f((u16)(u.x >> 16));
            sX[skq + 2][sr] = bf2f((u16)(u.y & 0xffffu)); sX[skq + 3][sr] = bf2f((u16)(u.y >> 16));
            sX[skq + 4][sr] = bf2f((u16)(u.z & 0xffffu)); sX[skq + 5][sr] = bf2f((u16)(u.z >> 16));
            sX[skq + 6][sr] = bf2f((u16)(u.w & 0xffffu)); sX[skq + 7][sr] = bf2f((u16)(u.w >> 16));
        }
        {
            const float* wp = W + (size_t)(kc + swk) * COLS + col0 + swn;
            float4 wa = *(const float4*)wp;
            float4 wb = *(const float4*)(wp + 4);
            *(float4*)&sW[swk][swn] = wa;
            *(float4*)&sW[swk][swn + 4] = wb;
        }
        __syncthreads();
#pragma unroll
        for (int k = 0; k < KC; ++k) {
            float4 a = *(const float4*)&sX[k][ty * 4];
            float4 b = *(const float4*)&sW[k][tx * 4];
            acc[0][0] += a.x * b.x; acc[0][1] += a.x * b.y; acc[0][2] += a.x * b.z; acc[0][3] += a.x * b.w;
            acc[1][0] += a.y * b.x; acc[1][1] += a.y * b.y; acc[1][2] += a.y * b.z; acc[1][3] += a.y * b.w;
            acc[2][0] += a.z * b.x; acc[2][1] += a.z * b.y; acc[2][2] += a.z * b.z; acc[2][3] += a.z * b.w;
            acc[3][0] += a.w * b.x; acc[3][1] += a.w * b.y; acc[3][2] += a.w * b.z; acc[3][3] += a.w * b.w;
        }
        __syncthreads();
    }

    int rbase = row0 + ty * 4;
#pragma unroll
    for (int i = 0; i < 4; ++i) {
        int gr = rbase + i;
        if (gr < nrows) {
            float s = rscale[gr];
            u32 lo = (u32)f2bf(acc[i][0] * s) | ((u32)f2bf(acc[i][1] * s) << 16);
            u32 hi = (u32)f2bf(acc[i][2] * s) | ((u32)f2bf(acc[i][3] * s) << 16);
            uint2 v; v.x = lo; v.y = hi;
            *(uint2*)&outp[(size_t)gr * COLS + col0 + tx * 4] = v;
        }
    }
}

// ---------------- SpMM over CSR: 256-dim, + bias + relu, bf16->bf16 ----------------
__global__ __launch_bounds__(256) void k_spmm_relu(const u16* __restrict__ A,
                                                   const int* __restrict__ rp,
                                                   const int* __restrict__ es,
                                                   const float* __restrict__ inorm,
                                                   const float* __restrict__ bias,
                                                   u16* __restrict__ B) {
    int row = blockIdx.x;
    int d = threadIdx.x;
    int beg = rp[row], end = rp[row + 1];
    float acc = 0.f;
    for (int i = beg; i < end; i += 8) {
        int n = end - i; if (n > 8) n = 8;
        int s[8];
#pragma unroll
        for (int j = 0; j < 8; ++j) s[j] = es[i + (j < n ? j : 0)];
#pragma unroll
        for (int j = 0; j < 8; ++j)
            if (j < n) acc += bf2f(A[(size_t)s[j] * 256 + d]);
    }
    float v = inorm[row] * acc + bias[d];
    B[(size_t)row * 256 + d] = f2bf(fmaxf(v, 0.f));
}

// ---------------- SpMM over CSR: 64-dim, + bias, bf16->fp32 out ----------------
__global__ __launch_bounds__(256) void k_spmm_out(const u16* __restrict__ Z,
                                                  const int* __restrict__ rp,
                                                  const int* __restrict__ es,
                                                  const float* __restrict__ inorm,
                                                  const float* __restrict__ bias,
                                                  float* __restrict__ out, int N) {
    int lane = threadIdx.x & 63;
    int row = blockIdx.x * 4 + (threadIdx.x >> 6);
    if (row >= N) return;
    int beg = rp[row], end = rp[row + 1];
    float acc = 0.f;
    for (int i = beg; i < end; i += 8) {
        int n = end - i; if (n > 8) n = 8;
        int s[8];
#pragma unroll
        for (int j = 0; j < 8; ++j) s[j] = es[i + (j < n ? j : 0)];
#pragma unroll
        for (int j = 0; j < 8; ++j)
            if (j < n) acc += bf2f(Z[(size_t)s[j] * 64 + lane]);
    }
    out[(size_t)row * 64 + lane] = inorm[row] * acc + bias[lane];
}

extern "C" void kernel_launch(void* const* d_in, const int* in_sizes, int n_in,
                              void* d_out, int out_size, void* d_ws, size_t ws_size,
                              hipStream_t stream) {
    const float* feat = (const float*)d_in[0];
    const float* W1   = (const float*)d_in[1];
    const float* b1   = (const float*)d_in[2];
    const float* W2   = (const float*)d_in[3];
    const float* b2   = (const float*)d_in[4];
    const int*   src  = (const int*)d_in[5];
    const int*   dst  = (const int*)d_in[6];

    const int DIN = 256;
    const int N = in_sizes[0] / DIN;   // 100000
    const int E = in_sizes[5];         // 3200000
    float* out = (float*)d_out;

    char* base = (char*)d_ws;
    size_t o = 0;
    auto take = [&](size_t b) { size_t r = o; o += (b + 255) & ~(size_t)255; return r; };
    int* outdeg = (int*)(base + take((size_t)N * 4));
    int* indeg  = (int*)(base + take((size_t)N * 4));
    int* cursor = (int*)(base + take((size_t)N * 4));
    size_t zero_bytes = o;   // zero the first three arrays in one memset
    float* onorm = (float*)(base + take((size_t)N * 4));
    float* inorm = (float*)(base + take((size_t)N * 4));
    int* bsum = (int*)(base + take(256 * 4));
    int* bsex = (int*)(base + take(256 * 4));
    int* rp   = (int*)(base + take((size_t)(N + 1) * 4));
    int* es   = (int*)(base + take((size_t)E * 4));
    u16* A    = (u16*)(base + take((size_t)N * 256 * 2));
    u16* B    = (u16*)(base + take((size_t)N * 256 * 2));
    u16* Z    = (u16*)(base + take((size_t)N * 64 * 2));
    (void)ws_size; (void)n_in; (void)out_size;

    hipMemsetAsync(base, 0, zero_bytes, stream);

    k_degrees<<<1024, 256, 0, stream>>>(src, dst, outdeg, indeg, E);
    k_norms<<<(N + 255) / 256, 256, 0, stream>>>(outdeg, indeg, onorm, inorm, N);

    int CH = (N + NSB - 1) / NSB;   // 400
    k_scan_partial<<<NSB, 256, 0, stream>>>(indeg, bsum, N, CH);
    k_scan_top<<<1, 256, 0, stream>>>(bsum, bsex, rp, N);
    k_scan_write<<<NSB, 256, (size_t)CH * 4, stream>>>(indeg, bsex, rp, N, CH);
    k_fill<<<1024, 256, 0, stream>>>(src, dst, rp, cursor, es, E);

    // layer 1: Z1 = (onorm*X)@W1  -> A (bf16), then h = relu(inorm*agg + b1) -> B
    dim3 g1((N + 63) / 64, 4);
    k_gemm_scale<256, false><<<g1, 256, 0, stream>>>(feat, W1, onorm, A, N);
    k_spmm_relu<<<N, 256, 0, stream>>>(A, rp, es, inorm, b1, B);

    // layer 2: Z2 = (onorm*h)@W2 -> Z (bf16), then out = inorm*agg + b2
    dim3 g2((N + 63) / 64, 1);
    k_gemm_scale<64, true><<<g2, 256, 0, stream>>>(B, W2, onorm, Z, N);
    k_spmm_out<<<(N + 3) / 4, 256, 0, stream>>>(Z, rp, es, inorm, b2, out, N);
}

// Round 2
// 890.263 us; speedup vs baseline: 1.7135x; 1.7135x over previous
//
#include <hip/hip_runtime.h>

typedef unsigned short u16;
typedef unsigned int u32;
typedef __attribute__((ext_vector_type(8))) short short8;
typedef __attribute__((ext_vector_type(4))) float f32x4;

#define NSB 250  // scan blocks

#define GLOAD_LDS16(g, l) \
    __builtin_amdgcn_global_load_lds((const __attribute__((address_space(1))) void*)(g), \
                                     (__attribute__((address_space(3))) void*)(l), 16, 0, 0)

__device__ __forceinline__ float bf2f(u16 h) {
    return __uint_as_float(((u32)h) << 16);
}
__device__ __forceinline__ u16 f2bf(float f) {
    u32 u = __float_as_uint(f);
    u += 0x7fffu + ((u >> 16) & 1u);   // round-to-nearest-even
    return (u16)(u >> 16);
}

// ---------------- degree histogram ----------------
__global__ void k_degrees(const int* __restrict__ src, const int* __restrict__ dst,
                          int* __restrict__ outdeg, int* __restrict__ indeg, int E) {
    int stride = gridDim.x * blockDim.x;
    for (int e = blockIdx.x * blockDim.x + threadIdx.x; e < E; e += stride) {
        atomicAdd(&outdeg[src[e]], 1);
        atomicAdd(&indeg[dst[e]], 1);
    }
}

__global__ void k_norms(const int* __restrict__ outdeg, const int* __restrict__ indeg,
                        float* __restrict__ onorm, float* __restrict__ inorm, int N) {
    int i = blockIdx.x * blockDim.x + threadIdx.x;
    if (i < N) {
        int od = outdeg[i]; if (od < 1) od = 1;
        int id = indeg[i];  if (id < 1) id = 1;
        onorm[i] = 1.0f / sqrtf((float)od);
        inorm[i] = 1.0f / sqrtf((float)id);
    }
}

// ---------------- Xb = bf16(onorm * X) ----------------
__global__ __launch_bounds__(256) void k_castx(const float* __restrict__ X,
                                               const float* __restrict__ onorm,
                                               u16* __restrict__ Xb, int total) {
    int stride = gridDim.x * blockDim.x * 4;
    for (int i = (blockIdx.x * blockDim.x + threadIdx.x) * 4; i < total; i += stride) {
        float4 v = *(const float4*)&X[i];
        float s = onorm[i >> 8];
        ushort4 o;
        o.x = f2bf(v.x * s); o.y = f2bf(v.y * s);
        o.z = f2bf(v.z * s); o.w = f2bf(v.w * s);
        *(ushort4*)&Xb[i] = o;
    }
}

// ---------------- Wt[c][k] = bf16(W[k][c]) ----------------
__global__ void k_wt(const float* __restrict__ W, u16* __restrict__ Wt, int K, int C) {
    int i = blockIdx.x * 256 + threadIdx.x;
    if (i < K * C) {
        int k = i / C, c = i - k * C;
        Wt[(size_t)c * K + k] = f2bf(W[i]);
    }
}

// ---------------- exclusive scan of indeg -> row_ptr ----------------
__global__ __launch_bounds__(256) void k_scan_partial(const int* __restrict__ indeg,
                                                      int* __restrict__ bsum, int N, int CH) {
    __shared__ int sh[256];
    int b = blockIdx.x, t = threadIdx.x;
    long base = (long)b * CH;
    int s = 0;
    for (int i = t; i < CH; i += 256) {
        long g = base + i;
        if (g < N) s += indeg[g];
    }
    sh[t] = s; __syncthreads();
    for (int off = 128; off > 0; off >>= 1) {
        if (t < off) sh[t] += sh[t + off];
        __syncthreads();
    }
    if (t == 0) bsum[b] = sh[0];
}

__global__ __launch_bounds__(256) void k_scan_top(const int* __restrict__ bsum,
                                                  int* __restrict__ bsex, int* __restrict__ rp, int N) {
    __shared__ int sh[256];
    int t = threadIdx.x;
    int v = (t < NSB) ? bsum[t] : 0;
    sh[t] = v; __syncthreads();
    for (int off = 1; off < 256; off <<= 1) {
        int x = (t >= off) ? sh[t - off] : 0;
        __syncthreads();
        sh[t] += x;
        __syncthreads();
    }
    bsex[t] = sh[t] - v;              // exclusive
    if (t == NSB - 1) rp[N] = sh[t];  // total = E
}

__global__ __launch_bounds__(256) void k_scan_write(const int* __restrict__ indeg,
                                                    const int* __restrict__ bsex,
                                                    int* __restrict__ rp, int N, int CH) {
    extern __shared__ int shc[];
    int b = blockIdx.x, t = threadIdx.x;
    long base = (long)b * CH;
    for (int i = t; i < CH; i += 256) shc[i] = (base + i < N) ? indeg[base + i] : 0;
    __syncthreads();
    if (t == 0) {
        int run = bsex[b];
        for (int i = 0; i < CH; ++i) { int x = shc[i]; shc[i] = run; run += x; }
    }
    __syncthreads();
    for (int i = t; i < CH; i += 256) if (base + i < N) rp[base + i] = shc[i];
}

// ---------------- CSR fill (dst-sorted src ids) ----------------
__global__ void k_fill(const int* __restrict__ src, const int* __restrict__ dst,
                       const int* __restrict__ rp, int* __restrict__ cursor,
                       int* __restrict__ es, int E) {
    int stride = gridDim.x * blockDim.x;
    for (int e = blockIdx.x * blockDim.x + threadIdx.x; e < E; e += stride) {
        int d = dst[e];
        int p = atomicAdd(&cursor[d], 1);
        es[rp[d] + p] = src[e];
    }
}

// ---------------- bf16 MFMA GEMM ----------------
// C[M][CT] = in[M][256] @ W[256][CT], in/W bf16, fp32 accum.
// in: GIN ? grouped [4][M][64] : row-major [M][256]
// Wt: pre-transposed [CT][256]
// out: GOUT ? grouped [4][M][64] bf16 : row-major [M][BN] bf16
// Block tile 128 x BN, 4 waves (WM x WN).
template <int BN, int WM, int WN, bool GIN, bool GOUT>
__global__ __launch_bounds__(256) void k_gemm(const u16* __restrict__ in,
                                              const u16* __restrict__ Wt,
                                              u16* __restrict__ outp, int M) {
    constexpr int WTM = 128 / WM, WTN = BN / WN;
    constexpr int FM = WTM / 16, FN = WTN / 16;
    constexpr int BROUNDS = (BN * 64) / 4096;

    __shared__ u16 sA[128][32];
    __shared__ u16 sB[BN][32];

    int t = threadIdx.x, wid = t >> 6, l = t & 63;
    int wr = wid / WN, wc = wid % WN;
    int r0 = blockIdx.x * 128;
    int c0 = blockIdx.y * BN;

    f32x4 acc[FM][FN] = {};

    for (int kc = 0; kc < 256; kc += 32) {
        // stage A tile: 8KB = 2 rounds of (256 threads x 16B)
#pragma unroll
        for (int r = 0; r < 2; ++r) {
            int off = r * 4096 + t * 16;
            int row = off >> 6;
            int ko = (off & 63) >> 1;
            int grow = r0 + row; if (grow >= M) grow = M - 1;
            const u16* gp = GIN ? in + ((size_t)(kc >> 6) * M + grow) * 64 + (kc & 63) + ko
                                : in + (size_t)grow * 256 + kc + ko;
            GLOAD_LDS16(gp, (char*)&sA[0][0] + r * 4096 + wid * 1024);
        }
        // stage B tile (transposed W: [col][k])
#pragma unroll
        for (int r = 0; r < BROUNDS; ++r) {
            int off = r * 4096 + t * 16;
            int col = off >> 6;
            int ko = (off & 63) >> 1;
            const u16* gp = Wt + (size_t)(c0 + col) * 256 + kc + ko;
            GLOAD_LDS16(gp, (char*)&sB[0][0] + r * 4096 + wid * 1024);
        }
        __syncthreads();

        short8 a[FM], b[FN];
#pragma unroll
        for (int m = 0; m < FM; ++m)
            a[m] = *(const short8*)&sA[wr * WTM + m * 16 + (l & 15)][(l >> 4) * 8];
#pragma unroll
        for (int n = 0; n < FN; ++n)
            b[n] = *(const short8*)&sB[wc * WTN + n * 16 + (l & 15)][(l >> 4) * 8];
#pragma unroll
        for (int m = 0; m < FM; ++m)
#pragma unroll
            for (int n = 0; n < FN; ++n)
                acc[m][n] = __builtin_amdgcn_mfma_f32_16x16x32_bf16(a[m], b[n], acc[m][n], 0, 0, 0);
        __syncthreads();
    }

    // epilogue: D layout col = lane&15, row = (lane>>4)*4 + e  [verified m89/m91]
#pragma unroll
    for (int m = 0; m < FM; ++m) {
#pragma unroll
        for (int n = 0; n < FN; ++n) {
#pragma unroll
            for (int e = 0; e < 4; ++e) {
                int row = r0 + wr * WTM + m * 16 + (l >> 4) * 4 + e;
                int col = c0 + wc * WTN + n * 16 + (l & 15);
                if (row < M) {
                    u16 v = f2bf(acc[m][n][e]);
                    if (GOUT) outp[((size_t)(col >> 6) * M + row) * 64 + (col & 63)] = v;
                    else      outp[(size_t)row * BN + col] = v;
                }
            }
        }
    }
}

// ---------------- SpMM layer 1: column-grouped, XCD-affine ----------------
// A4[4][N][64] -> B4[4][N][64];  B4[g][r] = bf16(onorm[r] * relu(inorm[r]*agg + b1[g*64+..]))
__global__ __launch_bounds__(256) void k_spmm1(const u16* __restrict__ A4,
                                               const int* __restrict__ rp,
                                               const int* __restrict__ es,
                                               const float* __restrict__ inorm,
                                               const float* __restrict__ onorm,
                                               const float* __restrict__ b1,
                                               u16* __restrict__ B4, int N) {
    int t = threadIdx.x, w = t >> 6, l = t & 63;
    int g = blockIdx.x & 3;               // blockIdx%8 -> XCD: group g lives on XCDs {g, g+4}
    int bi = blockIdx.x >> 2;
    int nb = gridDim.x >> 2;
    const u16* __restrict__ Ag = A4 + (size_t)g * N * 64;
    u16* __restrict__ Bg = B4 + (size_t)g * N * 64;
    float bias = b1[g * 64 + l];

    for (int r0 = bi * 4; r0 < N; r0 += nb * 4) {
        int row = r0 + w;
        if (row >= N) continue;
        int beg = rp[row], end = rp[row + 1];
        float acc = 0.f;
        for (int i = beg; i < end; i += 16) {
            int n = end - i; if (n > 16) n = 16;
            int s[16];
#pragma unroll
            for (int j = 0; j < 16; ++j) s[j] = es[i + (j < n ? j : 0)];
            float v[16];
#pragma unroll
            for (int j = 0; j < 16; ++j) v[j] = bf2f(Ag[(size_t)s[j] * 64 + l]);
#pragma unroll
            for (int j = 0; j < 16; ++j)
                if (j < n) acc += v[j];
        }
        float hv = inorm[row] * acc + bias;
        hv = fmaxf(hv, 0.f) * onorm[row];
        Bg[(size_t)row * 64 + l] = f2bf(hv);
    }
}

// ---------------- SpMM layer 2: 64-dim rows, wave per row ----------------
__global__ __launch_bounds__(256) void k_spmm_out(const u16* __restrict__ Z,
                                                  const int* __restrict__ rp,
                                                  const int* __restrict__ es,
                                                  const float* __restrict__ inorm,
                                                  const float* __restrict__ bias,
                                                  float* __restrict__ out, int N) {
    int t = threadIdx.x, w = t >> 6, l = t & 63;
    float b = bias[l];
    for (int r0 = blockIdx.x * 4; r0 < N; r0 += gridDim.x * 4) {
        int row = r0 + w;
        if (row >= N) continue;
        int beg = rp[row], end = rp[row + 1];
        float acc = 0.f;
        for (int i = beg; i < end; i += 16) {
            int n = end - i; if (n > 16) n = 16;
            int s[16];
#pragma unroll
            for (int j = 0; j < 16; ++j) s[j] = es[i + (j < n ? j : 0)];
            float v[16];
#pragma unroll
            for (int j = 0; j < 16; ++j) v[j] = bf2f(Z[(size_t)s[j] * 64 + l]);
#pragma unroll
            for (int j = 0; j < 16; ++j)
                if (j < n) acc += v[j];
        }
        out[(size_t)row * 64 + l] = inorm[row] * acc + b;
    }
}

extern "C" void kernel_launch(void* const* d_in, const int* in_sizes, int n_in,
                              void* d_out, int out_size, void* d_ws, size_t ws_size,
                              hipStream_t stream) {
    const float* feat = (const float*)d_in[0];
    const float* W1   = (const float*)d_in[1];
    const float* b1   = (const float*)d_in[2];
    const float* W2   = (const float*)d_in[3];
    const float* b2   = (const float*)d_in[4];
    const int*   src  = (const int*)d_in[5];
    const int*   dst  = (const int*)d_in[6];

    const int DIN = 256;
    const int N = in_sizes[0] / DIN;   // 100000
    const int E = in_sizes[5];         // 3200000
    float* out = (float*)d_out;

    char* base = (char*)d_ws;
    size_t o = 0;
    auto take = [&](size_t b) { size_t r = o; o += (b + 255) & ~(size_t)255; return r; };
    int* outdeg = (int*)(base + take((size_t)N * 4));
    int* indeg  = (int*)(base + take((size_t)N * 4));
    int* cursor = (int*)(base + take((size_t)N * 4));
    size_t zero_bytes = o;   // zero the first three arrays in one memset
    float* onorm = (float*)(base + take((size_t)N * 4));
    float* inorm = (float*)(base + take((size_t)N * 4));
    int* bsum = (int*)(base + take(256 * 4));
    int* bsex = (int*)(base + take(256 * 4));
    int* rp   = (int*)(base + take((size_t)(N + 1) * 4));
    u16* Wt1  = (u16*)(base + take((size_t)256 * 256 * 2));
    u16* Wt2  = (u16*)(base + take((size_t)64 * 256 * 2));
    int* es   = (int*)(base + take((size_t)E * 4));
    u16* S1   = (u16*)(base + take((size_t)N * 256 * 2));  // Xb, later B4
    u16* S2   = (u16*)(base + take((size_t)N * 256 * 2));  // A4
    u16* S3   = (u16*)(base + take((size_t)N * 64 * 2));   // Z
    (void)ws_size; (void)n_in; (void)out_size;

    u16* Xb = S1;
    u16* A4 = S2;
    u16* B4 = S1;
    u16* Z  = S3;

    hipMemsetAsync(base, 0, zero_bytes, stream);

    k_degrees<<<2048, 256, 0, stream>>>(src, dst, outdeg, indeg, E);
    k_norms<<<(N + 255) / 256, 256, 0, stream>>>(outdeg, indeg, onorm, inorm, N);
    k_castx<<<8192, 256, 0, stream>>>(feat, onorm, Xb, N * 256);
    k_wt<<<(256 * 256 + 255) / 256, 256, 0, stream>>>(W1, Wt1, 256, 256);
    k_wt<<<(256 * 64 + 255) / 256, 256, 0, stream>>>(W2, Wt2, 256, 64);

    int CH = (N + NSB - 1) / NSB;   // 400
    k_scan_partial<<<NSB, 256, 0, stream>>>(indeg, bsum, N, CH);
    k_scan_top<<<1, 256, 0, stream>>>(bsum, bsex, rp, N);
    k_scan_write<<<NSB, 256, (size_t)CH * 4, stream>>>(indeg, bsex, rp, N, CH);
    k_fill<<<2048, 256, 0, stream>>>(src, dst, rp, cursor, es, E);

    int mtiles = (N + 127) / 128;

    // layer 1: A4 = grouped(Xb @ W1)
    dim3 g1(mtiles, 2);
    k_gemm<128, 2, 2, false, true><<<g1, 256, 0, stream>>>(Xb, Wt1, A4, N);
    k_spmm1<<<8192, 256, 0, stream>>>(A4, rp, es, inorm, onorm, b1, B4, N);

    // layer 2: Z = B4 @ W2 (plain [N][64])
    dim3 g2(mtiles, 1);
    k_gemm<64, 4, 1, true, false><<<g2, 256, 0, stream>>>(B4, Wt2, Z, N);
    k_spmm_out<<<8192, 256, 0, stream>>>(Z, rp, es, inorm, b2, out, N);
}

// Round 3
// 798.768 us; speedup vs baseline: 1.9098x; 1.1145x over previous
//
#include <hip/hip_runtime.h>

typedef unsigned short u16;
typedef unsigned int u32;
typedef __attribute__((ext_vector_type(8))) short short8;
typedef __attribute__((ext_vector_type(4))) float f32x4;

#define NSB 250  // scan blocks

#define GLOAD_LDS16(g, l) \
    __builtin_amdgcn_global_load_lds((const __attribute__((address_space(1))) void*)(g), \
                                     (__attribute__((address_space(3))) void*)(l), 16, 0, 0)

__device__ __forceinline__ float bf2f(u16 h) {
    return __uint_as_float(((u32)h) << 16);
}
__device__ __forceinline__ u16 f2bf(float f) {
    u32 u = __float_as_uint(f);
    u += 0x7fffu + ((u >> 16) & 1u);   // round-to-nearest-even
    return (u16)(u >> 16);
}
__device__ __forceinline__ float bflo(u32 v) { return __uint_as_float(v << 16); }
__device__ __forceinline__ float bfhi(u32 v) { return __uint_as_float(v & 0xffff0000u); }

// ---------------- degree histogram ----------------
__global__ void k_degrees(const int* __restrict__ src, const int* __restrict__ dst,
                          int* __restrict__ outdeg, int* __restrict__ indeg, int E) {
    int stride = gridDim.x * blockDim.x;
    for (int e = blockIdx.x * blockDim.x + threadIdx.x; e < E; e += stride) {
        atomicAdd(&outdeg[src[e]], 1);
        atomicAdd(&indeg[dst[e]], 1);
    }
}

__global__ void k_norms(const int* __restrict__ outdeg, const int* __restrict__ indeg,
                        float* __restrict__ onorm, float* __restrict__ inorm, int N) {
    int i = blockIdx.x * blockDim.x + threadIdx.x;
    if (i < N) {
        int od = outdeg[i]; if (od < 1) od = 1;
        int id = indeg[i];  if (id < 1) id = 1;
        onorm[i] = 1.0f / sqrtf((float)od);
        inorm[i] = 1.0f / sqrtf((float)id);
    }
}

// ---------------- Xb = bf16(onorm * X) ----------------
__global__ __launch_bounds__(256) void k_castx(const float* __restrict__ X,
                                               const float* __restrict__ onorm,
                                               u16* __restrict__ Xb, int total) {
    int stride = gridDim.x * blockDim.x * 4;
    for (int i = (blockIdx.x * blockDim.x + threadIdx.x) * 4; i < total; i += stride) {
        float4 v = *(const float4*)&X[i];
        float s = onorm[i >> 8];
        ushort4 o;
        o.x = f2bf(v.x * s); o.y = f2bf(v.y * s);
        o.z = f2bf(v.z * s); o.w = f2bf(v.w * s);
        *(ushort4*)&Xb[i] = o;
    }
}

// ---------------- Wt[c][k] = bf16(W[k][c]) ----------------
__global__ void k_wt(const float* __restrict__ W, u16* __restrict__ Wt, int K, int C) {
    int i = blockIdx.x * 256 + threadIdx.x;
    if (i < K * C) {
        int k = i / C, c = i - k * C;
        Wt[(size_t)c * K + k] = f2bf(W[i]);
    }
}

// ---------------- exclusive scan of indeg -> row_ptr ----------------
__global__ __launch_bounds__(256) void k_scan_partial(const int* __restrict__ indeg,
                                                      int* __restrict__ bsum, int N, int CH) {
    __shared__ int sh[256];
    int b = blockIdx.x, t = threadIdx.x;
    long base = (long)b * CH;
    int s = 0;
    for (int i = t; i < CH; i += 256) {
        long g = base + i;
        if (g < N) s += indeg[g];
    }
    sh[t] = s; __syncthreads();
    for (int off = 128; off > 0; off >>= 1) {
        if (t < off) sh[t] += sh[t + off];
        __syncthreads();
    }
    if (t == 0) bsum[b] = sh[0];
}

__global__ __launch_bounds__(256) void k_scan_top(const int* __restrict__ bsum,
                                                  int* __restrict__ bsex, int* __restrict__ rp, int N) {
    __shared__ int sh[256];
    int t = threadIdx.x;
    int v = (t < NSB) ? bsum[t] : 0;
    sh[t] = v; __syncthreads();
    for (int off = 1; off < 256; off <<= 1) {
        int x = (t >= off) ? sh[t - off] : 0;
        __syncthreads();
        sh[t] += x;
        __syncthreads();
    }
    bsex[t] = sh[t] - v;              // exclusive
    if (t == NSB - 1) rp[N] = sh[t];  // total = E
}

__global__ __launch_bounds__(256) void k_scan_write(const int* __restrict__ indeg,
                                                    const int* __restrict__ bsex,
                                                    int* __restrict__ rp, int N, int CH) {
    extern __shared__ int shc[];
    int b = blockIdx.x, t = threadIdx.x;
    long base = (long)b * CH;
    for (int i = t; i < CH; i += 256) shc[i] = (base + i < N) ? indeg[base + i] : 0;
    __syncthreads();
    if (t == 0) {
        int run = bsex[b];
        for (int i = 0; i < CH; ++i) { int x = shc[i]; shc[i] = run; run += x; }
    }
    __syncthreads();
    for (int i = t; i < CH; i += 256) if (base + i < N) rp[base + i] = shc[i];
}

// ---------------- CSR fill: es = src<<7 (byte offset, 128B row stride) ----------------
__global__ void k_fill(const int* __restrict__ src, const int* __restrict__ dst,
                       const int* __restrict__ rp, int* __restrict__ cursor,
                       int* __restrict__ es, int E) {
    int stride = gridDim.x * blockDim.x;
    for (int e = blockIdx.x * blockDim.x + threadIdx.x; e < E; e += stride) {
        int d = dst[e];
        int p = atomicAdd(&cursor[d], 1);
        es[rp[d] + p] = src[e] << 7;
    }
}

// ---------------- bf16 MFMA GEMM ----------------
// C[M][CT] = in[M][256] @ W[256][CT], in/W bf16, fp32 accum.
// in: GIN ? grouped [2][M][128] : row-major [M][256]
// Wt: pre-transposed [CT][256]
// out: GOUT ? grouped [2][M][128] bf16 : row-major [M][BN] bf16
// Block tile 128 x BN, 4 waves (WM x WN).
template <int BN, int WM, int WN, bool GIN, bool GOUT>
__global__ __launch_bounds__(256) void k_gemm(const u16* __restrict__ in,
                                              const u16* __restrict__ Wt,
                                              u16* __restrict__ outp, int M) {
    constexpr int WTM = 128 / WM, WTN = BN / WN;
    constexpr int FM = WTM / 16, FN = WTN / 16;
    constexpr int BROUNDS = (BN * 64) / 4096;

    __shared__ u16 sA[128][32];
    __shared__ u16 sB[BN][32];

    int t = threadIdx.x, wid = t >> 6, l = t & 63;
    int wr = wid / WN, wc = wid % WN;
    int r0 = blockIdx.x * 128;
    int c0 = blockIdx.y * BN;

    f32x4 acc[FM][FN] = {};

    for (int kc = 0; kc < 256; kc += 32) {
        // stage A tile: 8KB = 2 rounds of (256 threads x 16B)
#pragma unroll
        for (int r = 0; r < 2; ++r) {
            int off = r * 4096 + t * 16;
            int row = off >> 6;
            int ko = (off & 63) >> 1;
            int grow = r0 + row; if (grow >= M) grow = M - 1;
            const u16* gp = GIN ? in + ((size_t)(kc >> 7) * M + grow) * 128 + (kc & 127) + ko
                                : in + (size_t)grow * 256 + kc + ko;
            GLOAD_LDS16(gp, (char*)&sA[0][0] + r * 4096 + wid * 1024);
        }
        // stage B tile (transposed W: [col][k])
#pragma unroll
        for (int r = 0; r < BROUNDS; ++r) {
            int off = r * 4096 + t * 16;
            int col = off >> 6;
            int ko = (off & 63) >> 1;
            const u16* gp = Wt + (size_t)(c0 + col) * 256 + kc + ko;
            GLOAD_LDS16(gp, (char*)&sB[0][0] + r * 4096 + wid * 1024);
        }
        __syncthreads();

        short8 a[FM], b[FN];
#pragma unroll
        for (int m = 0; m < FM; ++m)
            a[m] = *(const short8*)&sA[wr * WTM + m * 16 + (l & 15)][(l >> 4) * 8];
#pragma unroll
        for (int n = 0; n < FN; ++n)
            b[n] = *(const short8*)&sB[wc * WTN + n * 16 + (l & 15)][(l >> 4) * 8];
#pragma unroll
        for (int m = 0; m < FM; ++m)
#pragma unroll
            for (int n = 0; n < FN; ++n)
                acc[m][n] = __builtin_amdgcn_mfma_f32_16x16x32_bf16(a[m], b[n], acc[m][n], 0, 0, 0);
        __syncthreads();
    }

    // epilogue: D layout col = lane&15, row = (lane>>4)*4 + e  [verified m89/m91]
#pragma unroll
    for (int m = 0; m < FM; ++m) {
#pragma unroll
        for (int n = 0; n < FN; ++n) {
#pragma unroll
            for (int e = 0; e < 4; ++e) {
                int row = r0 + wr * WTM + m * 16 + (l >> 4) * 4 + e;
                int col = c0 + wc * WTN + n * 16 + (l & 15);
                if (row < M) {
                    u16 v = f2bf(acc[m][n][e]);
                    if (GOUT) outp[((size_t)(col >> 7) * M + row) * 128 + (col & 127)] = v;
                    else      outp[(size_t)row * BN + col] = v;
                }
            }
        }
    }
}

// ---------------- SpMM layer 1: 128-col groups, dword gathers ----------------
// A2[2][N][128] -> B2[2][N][128]
// B2[g][r][2l..2l+1] = bf16(onorm[r] * relu(inorm[r]*agg + b1[g*128+2l..]))
__global__ __launch_bounds__(256) void k_spmm1(const u16* __restrict__ A2,
                                               const int* __restrict__ rp,
                                               const int* __restrict__ es,
                                               const float* __restrict__ inorm,
                                               const float* __restrict__ onorm,
                                               const float* __restrict__ b1,
                                               u16* __restrict__ B2, int N) {
    int t = threadIdx.x, w = t >> 6, l = t & 63;
    int g = blockIdx.x & 1;               // group g on 4 of 8 XCDs
    int bi = blockIdx.x >> 1;
    int nb = gridDim.x >> 1;
    const char* __restrict__ Ag = (const char*)(A2 + (size_t)g * N * 128);
    char* __restrict__ Bg = (char*)(B2 + (size_t)g * N * 128);
    float bias0 = b1[g * 128 + 2 * l];
    float bias1 = b1[g * 128 + 2 * l + 1];
    u32 lo4 = (u32)l * 4;

    for (int r0 = bi * 4; r0 < N; r0 += nb * 4) {
        int row = r0 + w;
        if (row >= N) continue;
        int beg = rp[row], end = rp[row + 1];
        float a0 = 0.f, a1 = 0.f;
        int i = beg;
        // full 16-edge blocks, no predication
        for (; i + 16 <= end; i += 16) {
            int s[16];
#pragma unroll
            for (int j = 0; j < 16; ++j) s[j] = es[i + j];
            u32 v[16];
#pragma unroll
            for (int j = 0; j < 16; ++j)
                v[j] = *(const u32*)(Ag + (((u32)s[j] << 1) + lo4));
#pragma unroll
            for (int j = 0; j < 16; ++j) { a0 += bflo(v[j]); a1 += bfhi(v[j]); }
        }
        // remainder block, predicated
        int n = end - i;
        if (n > 0) {
            int s[16];
#pragma unroll
            for (int j = 0; j < 16; ++j) s[j] = es[i + (j < n ? j : 0)];
            u32 v[16];
#pragma unroll
            for (int j = 0; j < 16; ++j)
                v[j] = *(const u32*)(Ag + (((u32)s[j] << 1) + lo4));
#pragma unroll
            for (int j = 0; j < 16; ++j)
                if (j < n) { a0 += bflo(v[j]); a1 += bfhi(v[j]); }
        }
        float in_ = inorm[row], on_ = onorm[row];
        float h0 = fmaxf(in_ * a0 + bias0, 0.f) * on_;
        float h1 = fmaxf(in_ * a1 + bias1, 0.f) * on_;
        u32 pack = (u32)f2bf(h0) | ((u32)f2bf(h1) << 16);
        *(u32*)(Bg + (size_t)row * 256 + lo4) = pack;
    }
}

// ---------------- SpMM layer 2: 64-dim rows, wave per row ----------------
__global__ __launch_bounds__(256) void k_spmm_out(const u16* __restrict__ Z,
                                                  const int* __restrict__ rp,
                                                  const int* __restrict__ es,
                                                  const float* __restrict__ inorm,
                                                  const float* __restrict__ bias,
                                                  float* __restrict__ out, int N) {
    int t = threadIdx.x, w = t >> 6, l = t & 63;
    float b = bias[l];
    const char* __restrict__ Zc = (const char*)Z;
    u32 lo2 = (u32)l * 2;
    for (int r0 = blockIdx.x * 4; r0 < N; r0 += gridDim.x * 4) {
        int row = r0 + w;
        if (row >= N) continue;
        int beg = rp[row], end = rp[row + 1];
        float acc = 0.f;
        int i = beg;
        for (; i + 16 <= end; i += 16) {
            int s[16];
#pragma unroll
            for (int j = 0; j < 16; ++j) s[j] = es[i + j];
            u16 v[16];
#pragma unroll
            for (int j = 0; j < 16; ++j)
                v[j] = *(const u16*)(Zc + ((u32)s[j] + lo2));
#pragma unroll
            for (int j = 0; j < 16; ++j) acc += bf2f(v[j]);
        }
        int n = end - i;
        if (n > 0) {
            int s[16];
#pragma unroll
            for (int j = 0; j < 16; ++j) s[j] = es[i + (j < n ? j : 0)];
            u16 v[16];
#pragma unroll
            for (int j = 0; j < 16; ++j)
                v[j] = *(const u16*)(Zc + ((u32)s[j] + lo2));
#pragma unroll
            for (int j = 0; j < 16; ++j)
                if (j < n) acc += bf2f(v[j]);
        }
        out[(size_t)row * 64 + l] = inorm[row] * acc + b;
    }
}

extern "C" void kernel_launch(void* const* d_in, const int* in_sizes, int n_in,
                              void* d_out, int out_size, void* d_ws, size_t ws_size,
                              hipStream_t stream) {
    const float* feat = (const float*)d_in[0];
    const float* W1   = (const float*)d_in[1];
    const float* b1   = (const float*)d_in[2];
    const float* W2   = (const float*)d_in[3];
    const float* b2   = (const float*)d_in[4];
    const int*   src  = (const int*)d_in[5];
    const int*   dst  = (const int*)d_in[6];

    const int DIN = 256;
    const int N = in_sizes[0] / DIN;   // 100000
    const int E = in_sizes[5];         // 3200000
    float* out = (float*)d_out;

    char* base = (char*)d_ws;
    size_t o = 0;
    auto take = [&](size_t b) { size_t r = o; o += (b + 255) & ~(size_t)255; return r; };
    int* outdeg = (int*)(base + take((size_t)N * 4));
    int* indeg  = (int*)(base + take((size_t)N * 4));
    int* cursor = (int*)(base + take((size_t)N * 4));
    size_t zero_bytes = o;   // zero the first three arrays in one memset
    float* onorm = (float*)(base + take((size_t)N * 4));
    float* inorm = (float*)(base + take((size_t)N * 4));
    int* bsum = (int*)(base + take(256 * 4));
    int* bsex = (int*)(base + take(256 * 4));
    int* rp   = (int*)(base + take((size_t)(N + 1) * 4));
    u16* Wt1  = (u16*)(base + take((size_t)256 * 256 * 2));
    u16* Wt2  = (u16*)(base + take((size_t)64 * 256 * 2));
    int* es   = (int*)(base + take((size_t)E * 4));
    u16* S1   = (u16*)(base + take((size_t)N * 256 * 2));  // Xb, later B2
    u16* S2   = (u16*)(base + take((size_t)N * 256 * 2));  // A2
    u16* S3   = (u16*)(base + take((size_t)N * 64 * 2));   // Z
    (void)ws_size; (void)n_in; (void)out_size;

    u16* Xb = S1;
    u16* A2 = S2;
    u16* B2 = S1;
    u16* Z  = S3;

    hipMemsetAsync(base, 0, zero_bytes, stream);

    k_degrees<<<2048, 256, 0, stream>>>(src, dst, outdeg, indeg, E);
    k_norms<<<(N + 255) / 256, 256, 0, stream>>>(outdeg, indeg, onorm, inorm, N);
    k_castx<<<8192, 256, 0, stream>>>(feat, onorm, Xb, N * 256);
    k_wt<<<(256 * 256 + 255) / 256, 256, 0, stream>>>(W1, Wt1, 256, 256);
    k_wt<<<(256 * 64 + 255) / 256, 256, 0, stream>>>(W2, Wt2, 256, 64);

    int CH = (N + NSB - 1) / NSB;   // 400
    k_scan_partial<<<NSB, 256, 0, stream>>>(indeg, bsum, N, CH);
    k_scan_top<<<1, 256, 0, stream>>>(bsum, bsex, rp, N);
    k_scan_write<<<NSB, 256, (size_t)CH * 4, stream>>>(indeg, bsex, rp, N, CH);
    k_fill<<<2048, 256, 0, stream>>>(src, dst, rp, cursor, es, E);

    int mtiles = (N + 127) / 128;

    // layer 1: A2 = grouped(Xb @ W1)
    dim3 g1(mtiles, 2);
    k_gemm<128, 2, 2, false, true><<<g1, 256, 0, stream>>>(Xb, Wt1, A2, N);
    k_spmm1<<<8192, 256, 0, stream>>>(A2, rp, es, inorm, onorm, b1, B2, N);

    // layer 2: Z = B2 @ W2 (plain [N][64])
    dim3 g2(mtiles, 1);
    k_gemm<64, 4, 1, true, false><<<g2, 256, 0, stream>>>(B2, Wt2, Z, N);
    k_spmm_out<<<8192, 256, 0, stream>>>(Z, rp, es, inorm, b2, out, N);
}

// Round 5
// 721.519 us; speedup vs baseline: 2.1142x; 1.1071x over previous
//
#include <hip/hip_runtime.h>

typedef unsigned short u16;
typedef unsigned int u32;
typedef __attribute__((ext_vector_type(8))) short short8;
typedef __attribute__((ext_vector_type(4))) float f32x4;

#define NSB 250  // scan blocks

#define GLOAD_LDS16(g, l) \
    __builtin_amdgcn_global_load_lds((const __attribute__((address_space(1))) void*)(g), \
                                     (__attribute__((address_space(3))) void*)(l), 16, 0, 0)

#define WG_ATOMIC_ADD(p, v) \
    __hip_atomic_fetch_add((p), (v), __ATOMIC_RELAXED, __HIP_MEMORY_SCOPE_WORKGROUP)

__device__ __forceinline__ float bf2f(u16 h) {
    return __uint_as_float(((u32)h) << 16);
}
__device__ __forceinline__ u16 f2bf(float f) {
    u32 u = __float_as_uint(f);
    u += 0x7fffu + ((u >> 16) & 1u);   // round-to-nearest-even
    return (u16)(u >> 16);
}
__device__ __forceinline__ float bflo(u32 v) { return __uint_as_float(v << 16); }
__device__ __forceinline__ float bfhi(u32 v) { return __uint_as_float(v & 0xffff0000u); }

__device__ __forceinline__ u32 xcd_id() {
    u32 x;
    asm volatile("s_getreg_b32 %0, hwreg(HW_REG_XCC_ID)" : "=s"(x));
    return x & 7;
}

// ---------------- pass 1: XCD-privatized degree histograms + slot tags ----------------
__global__ __launch_bounds__(256) void k_count(const int* __restrict__ src,
                                               const int* __restrict__ dst,
                                               u32* __restrict__ outdeg8,
                                               u32* __restrict__ cnt8,
                                               u32* __restrict__ tag, int E, int N) {
    u32 p = xcd_id();
    u32* __restrict__ od = outdeg8 + (size_t)p * N;
    u32* __restrict__ ct = cnt8 + (size_t)p * N;
    int stride = gridDim.x * blockDim.x * 4;
    for (int e = (blockIdx.x * blockDim.x + threadIdx.x) * 4; e < E; e += stride) {
        if (e + 4 <= E) {
            int4 s4 = *(const int4*)&src[e];
            int4 d4 = *(const int4*)&dst[e];
            WG_ATOMIC_ADD(&od[s4.x], 1u);
            WG_ATOMIC_ADD(&od[s4.y], 1u);
            WG_ATOMIC_ADD(&od[s4.z], 1u);
            WG_ATOMIC_ADD(&od[s4.w], 1u);
            u32 l0 = WG_ATOMIC_ADD(&ct[d4.x], 1u);
            u32 l1 = WG_ATOMIC_ADD(&ct[d4.y], 1u);
            u32 l2 = WG_ATOMIC_ADD(&ct[d4.z], 1u);
            u32 l3 = WG_ATOMIC_ADD(&ct[d4.w], 1u);
            uint4 t4; t4.x = (l0 << 3) | p; t4.y = (l1 << 3) | p;
            t4.z = (l2 << 3) | p; t4.w = (l3 << 3) | p;
            *(uint4*)&tag[e] = t4;
        } else {
            for (int k = e; k < E; ++k) {
                WG_ATOMIC_ADD(&od[src[k]], 1u);
                u32 l = WG_ATOMIC_ADD(&ct[dst[k]], 1u);
                tag[k] = (l << 3) | p;
            }
        }
    }
}

// ---------------- pass 2: merge 8 copies, exclusive prefix over XCDs, norms ----------------
__global__ __launch_bounds__(256) void k_merge(u32* __restrict__ outdeg8,
                                               u32* __restrict__ cnt8,
                                               int* __restrict__ indeg,
                                               float* __restrict__ onorm,
                                               float* __restrict__ inorm, int N) {
    int i = blockIdx.x * 256 + threadIdx.x;
    if (i >= N) return;
    u32 od = 0;
#pragma unroll
    for (int x = 0; x < 8; ++x) od += outdeg8[(size_t)x * N + i];
    u32 run = 0;
#pragma unroll
    for (int x = 0; x < 8; ++x) {
        u32 c = cnt8[(size_t)x * N + i];
        cnt8[(size_t)x * N + i] = run;
        run += c;
    }
    indeg[i] = (int)run;
    int odc = od < 1u ? 1 : (int)od;
    int idc = run < 1u ? 1 : (int)run;
    onorm[i] = 1.0f / sqrtf((float)odc);
    inorm[i] = 1.0f / sqrtf((float)idc);
}

// cnt8[x][i] += rp[i]  ->  cnt8 becomes absolute slot base per (xcd, node)
__global__ __launch_bounds__(256) void k_rpb(u32* __restrict__ cnt8,
                                             const int* __restrict__ rp, int N) {
    int i = blockIdx.x * 256 + threadIdx.x;
    if (i < N) cnt8[(size_t)blockIdx.y * N + i] += (u32)rp[i];
}

// ---------------- pass 3: atomic-free CSR placement ----------------
__global__ __launch_bounds__(256) void k_place(const int* __restrict__ src,
                                               const int* __restrict__ dst,
                                               const u32* __restrict__ tag,
                                               const u32* __restrict__ cnt8,
                                               int* __restrict__ es, int E, int N) {
    int stride = gridDim.x * blockDim.x * 4;
    for (int e = (blockIdx.x * blockDim.x + threadIdx.x) * 4; e < E; e += stride) {
        if (e + 4 <= E) {
            int4 s4 = *(const int4*)&src[e];
            int4 d4 = *(const int4*)&dst[e];
            uint4 t4 = *(const uint4*)&tag[e];
            es[cnt8[(size_t)(t4.x & 7) * N + d4.x] + (t4.x >> 3)] = s4.x << 7;
            es[cnt8[(size_t)(t4.y & 7) * N + d4.y] + (t4.y >> 3)] = s4.y << 7;
            es[cnt8[(size_t)(t4.z & 7) * N + d4.z] + (t4.z >> 3)] = s4.z << 7;
            es[cnt8[(size_t)(t4.w & 7) * N + d4.w] + (t4.w >> 3)] = s4.w << 7;
        } else {
            for (int k = e; k < E; ++k) {
                u32 t = tag[k];
                es[cnt8[(size_t)(t & 7) * N + dst[k]] + (t >> 3)] = src[k] << 7;
            }
        }
    }
}

// ---------------- Xb = bf16(onorm * X) ----------------
__global__ __launch_bounds__(256) void k_castx(const float* __restrict__ X,
                                               const float* __restrict__ onorm,
                                               u16* __restrict__ Xb, int total) {
    int stride = gridDim.x * blockDim.x * 4;
    for (int i = (blockIdx.x * blockDim.x + threadIdx.x) * 4; i < total; i += stride) {
        float4 v = *(const float4*)&X[i];
        float s = onorm[i >> 8];
        ushort4 o;
        o.x = f2bf(v.x * s); o.y = f2bf(v.y * s);
        o.z = f2bf(v.z * s); o.w = f2bf(v.w * s);
        *(ushort4*)&Xb[i] = o;
    }
}

// ---------------- Wt[c][k] = bf16(W[k][c]) ----------------
__global__ void k_wt(const float* __restrict__ W, u16* __restrict__ Wt, int K, int C) {
    int i = blockIdx.x * 256 + threadIdx.x;
    if (i < K * C) {
        int k = i / C, c = i - k * C;
        Wt[(size_t)c * K + k] = f2bf(W[i]);
    }
}

// ---------------- exclusive scan of indeg -> row_ptr ----------------
__global__ __launch_bounds__(256) void k_scan_partial(const int* __restrict__ indeg,
                                                      int* __restrict__ bsum, int N, int CH) {
    __shared__ int sh[256];
    int b = blockIdx.x, t = threadIdx.x;
    long base = (long)b * CH;
    int s = 0;
    for (int i = t; i < CH; i += 256) {
        long g = base + i;
        if (g < N) s += indeg[g];
    }
    sh[t] = s; __syncthreads();
    for (int off = 128; off > 0; off >>= 1) {
        if (t < off) sh[t] += sh[t + off];
        __syncthreads();
    }
    if (t == 0) bsum[b] = sh[0];
}

__global__ __launch_bounds__(256) void k_scan_top(const int* __restrict__ bsum,
                                                  int* __restrict__ bsex, int* __restrict__ rp, int N) {
    __shared__ int sh[256];
    int t = threadIdx.x;
    int v = (t < NSB) ? bsum[t] : 0;
    sh[t] = v; __syncthreads();
    for (int off = 1; off < 256; off <<= 1) {
        int x = (t >= off) ? sh[t - off] : 0;
        __syncthreads();
        sh[t] += x;
        __syncthreads();
    }
    bsex[t] = sh[t] - v;              // exclusive
    if (t == NSB - 1) rp[N] = sh[t];  // total = E
}

__global__ __launch_bounds__(256) void k_scan_write(const int* __restrict__ indeg,
                                                    const int* __restrict__ bsex,
                                                    int* __restrict__ rp, int N, int CH) {
    extern __shared__ int shc[];
    int b = blockIdx.x, t = threadIdx.x;
    long base = (long)b * CH;
    for (int i = t; i < CH; i += 256) shc[i] = (base + i < N) ? indeg[base + i] : 0;
    __syncthreads();
    if (t == 0) {
        int run = bsex[b];
        for (int i = 0; i < CH; ++i) { int x = shc[i]; shc[i] = run; run += x; }
    }
    __syncthreads();
    for (int i = t; i < CH; i += 256) if (base + i < N) rp[base + i] = shc[i];
}

// ---------------- bf16 MFMA GEMM ----------------
// C[M][CT] = in[M][256] @ W[256][CT], in/W bf16, fp32 accum.
// in: GIN ? grouped [2][M][128] : row-major [M][256]
// Wt: pre-transposed [CT][256]
// out: GOUT ? grouped [2][M][128] bf16 : row-major [M][BN] bf16
// Block tile 128 x BN, 4 waves (WM x WN).
template <int BN, int WM, int WN, bool GIN, bool GOUT>
__global__ __launch_bounds__(256) void k_gemm(const u16* __restrict__ in,
                                              const u16* __restrict__ Wt,
                                              u16* __restrict__ outp, int M) {
    constexpr int WTM = 128 / WM, WTN = BN / WN;
    constexpr int FM = WTM / 16, FN = WTN / 16;
    constexpr int BROUNDS = (BN * 64) / 4096;

    __shared__ u16 sA[128][32];
    __shared__ u16 sB[BN][32];

    int t = threadIdx.x, wid = t >> 6, l = t & 63;
    int wr = wid / WN, wc = wid % WN;
    int r0 = blockIdx.x * 128;
    int c0 = blockIdx.y * BN;

    f32x4 acc[FM][FN] = {};

    for (int kc = 0; kc < 256; kc += 32) {
        // stage A tile: 8KB = 2 rounds of (256 threads x 16B)
#pragma unroll
        for (int r = 0; r < 2; ++r) {
            int off = r * 4096 + t * 16;
            int row = off >> 6;
            int ko = (off & 63) >> 1;
            int grow = r0 + row; if (grow >= M) grow = M - 1;
            const u16* gp = GIN ? in + ((size_t)(kc >> 7) * M + grow) * 128 + (kc & 127) + ko
                                : in + (size_t)grow * 256 + kc + ko;
            GLOAD_LDS16(gp, (char*)&sA[0][0] + r * 4096 + wid * 1024);
        }
        // stage B tile (transposed W: [col][k])
#pragma unroll
        for (int r = 0; r < BROUNDS; ++r) {
            int off = r * 4096 + t * 16;
            int col = off >> 6;
            int ko = (off & 63) >> 1;
            const u16* gp = Wt + (size_t)(c0 + col) * 256 + kc + ko;
            GLOAD_LDS16(gp, (char*)&sB[0][0] + r * 4096 + wid * 1024);
        }
        __syncthreads();

        short8 a[FM], b[FN];
#pragma unroll
        for (int m = 0; m < FM; ++m)
            a[m] = *(const short8*)&sA[wr * WTM + m * 16 + (l & 15)][(l >> 4) * 8];
#pragma unroll
        for (int n = 0; n < FN; ++n)
            b[n] = *(const short8*)&sB[wc * WTN + n * 16 + (l & 15)][(l >> 4) * 8];
#pragma unroll
        for (int m = 0; m < FM; ++m)
#pragma unroll
            for (int n = 0; n < FN; ++n)
                acc[m][n] = __builtin_amdgcn_mfma_f32_16x16x32_bf16(a[m], b[n], acc[m][n], 0, 0, 0);
        __syncthreads();
    }

    // epilogue: D layout col = lane&15, row = (lane>>4)*4 + e  [verified m89/m91]
#pragma unroll
    for (int m = 0; m < FM; ++m) {
#pragma unroll
        for (int n = 0; n < FN; ++n) {
#pragma unroll
            for (int e = 0; e < 4; ++e) {
                int row = r0 + wr * WTM + m * 16 + (l >> 4) * 4 + e;
                int col = c0 + wc * WTN + n * 16 + (l & 15);
                if (row < M) {
                    u16 v = f2bf(acc[m][n][e]);
                    if (GOUT) outp[((size_t)(col >> 7) * M + row) * 128 + (col & 127)] = v;
                    else      outp[(size_t)row * BN + col] = v;
                }
            }
        }
    }
}

// ---------------- SpMM layer 1: 128-col groups, dword gathers ----------------
// A2[2][N][128] -> B2[2][N][128]
// B2[g][r][2l..2l+1] = bf16(onorm[r] * relu(inorm[r]*agg + b1[g*128+2l..]))
__global__ __launch_bounds__(256) void k_spmm1(const u16* __restrict__ A2,
                                               const int* __restrict__ rp,
                                               const int* __restrict__ es,
                                               const float* __restrict__ inorm,
                                               const float* __restrict__ onorm,
                                               const float* __restrict__ b1,
                                               u16* __restrict__ B2, int N) {
    int t = threadIdx.x, w = t >> 6, l = t & 63;
    int g = blockIdx.x & 1;               // group g on 4 of 8 XCDs
    int bi = blockIdx.x >> 1;
    int nb = gridDim.x >> 1;
    const char* __restrict__ Ag = (const char*)(A2 + (size_t)g * N * 128);
    char* __restrict__ Bg = (char*)(B2 + (size_t)g * N * 128);
    float bias0 = b1[g * 128 + 2 * l];
    float bias1 = b1[g * 128 + 2 * l + 1];
    u32 lo4 = (u32)l * 4;

    for (int r0 = bi * 4; r0 < N; r0 += nb * 4) {
        int row = r0 + w;
        if (row >= N) continue;
        int beg = rp[row], end = rp[row + 1];
        float a0 = 0.f, a1 = 0.f;
        int i = beg;
        // full 16-edge blocks, no predication
        for (; i + 16 <= end; i += 16) {
            int s[16];
#pragma unroll
            for (int j = 0; j < 16; ++j) s[j] = es[i + j];
            u32 v[16];
#pragma unroll
            for (int j = 0; j < 16; ++j)
                v[j] = *(const u32*)(Ag + (((u32)s[j] << 1) + lo4));
#pragma unroll
            for (int j = 0; j < 16; ++j) { a0 += bflo(v[j]); a1 += bfhi(v[j]); }
        }
        // remainder block, predicated
        int n = end - i;
        if (n > 0) {
            int s[16];
#pragma unroll
            for (int j = 0; j < 16; ++j) s[j] = es[i + (j < n ? j : 0)];
            u32 v[16];
#pragma unroll
            for (int j = 0; j < 16; ++j)
                v[j] = *(const u32*)(Ag + (((u32)s[j] << 1) + lo4));
#pragma unroll
            for (int j = 0; j < 16; ++j)
                if (j < n) { a0 += bflo(v[j]); a1 += bfhi(v[j]); }
        }
        float in_ = inorm[row], on_ = onorm[row];
        float h0 = fmaxf(in_ * a0 + bias0, 0.f) * on_;
        float h1 = fmaxf(in_ * a1 + bias1, 0.f) * on_;
        u32 pack = (u32)f2bf(h0) | ((u32)f2bf(h1) << 16);
        *(u32*)(Bg + (size_t)row * 256 + lo4) = pack;
    }
}

// ---------------- SpMM layer 2: 64-dim rows, wave per row ----------------
__global__ __launch_bounds__(256) void k_spmm_out(const u16* __restrict__ Z,
                                                  const int* __restrict__ rp,
                                                  const int* __restrict__ es,
                                                  const float* __restrict__ inorm,
                                                  const float* __restrict__ bias,
                                                  float* __restrict__ out, int N) {
    int t = threadIdx.x, w = t >> 6, l = t & 63;
    float b = bias[l];
    const char* __restrict__ Zc = (const char*)Z;
    u32 lo2 = (u32)l * 2;
    for (int r0 = blockIdx.x * 4; r0 < N; r0 += gridDim.x * 4) {
        int row = r0 + w;
        if (row >= N) continue;
        int beg = rp[row], end = rp[row + 1];
        float acc = 0.f;
        int i = beg;
        for (; i + 16 <= end; i += 16) {
            int s[16];
#pragma unroll
            for (int j = 0; j < 16; ++j) s[j] = es[i + j];
            u16 v[16];
#pragma unroll
            for (int j = 0; j < 16; ++j)
                v[j] = *(const u16*)(Zc + ((u32)s[j] + lo2));
#pragma unroll
            for (int j = 0; j < 16; ++j) acc += bf2f(v[j]);
        }
        int n = end - i;
        if (n > 0) {
            int s[16];
#pragma unroll
            for (int j = 0; j < 16; ++j) s[j] = es[i + (j < n ? j : 0)];
            u16 v[16];
#pragma unroll
            for (int j = 0; j < 16; ++j)
                v[j] = *(const u16*)(Zc + ((u32)s[j] + lo2));
#pragma unroll
            for (int j = 0; j < 16; ++j)
                if (j < n) acc += bf2f(v[j]);
        }
        out[(size_t)row * 64 + l] = inorm[row] * acc + b;
    }
}

extern "C" void kernel_launch(void* const* d_in, const int* in_sizes, int n_in,
                              void* d_out, int out_size, void* d_ws, size_t ws_size,
                              hipStream_t stream) {
    const float* feat = (const float*)d_in[0];
    const float* W1   = (const float*)d_in[1];
    const float* b1   = (const float*)d_in[2];
    const float* W2   = (const float*)d_in[3];
    const float* b2   = (const float*)d_in[4];
    const int*   src  = (const int*)d_in[5];
    const int*   dst  = (const int*)d_in[6];

    const int DIN = 256;
    const int N = in_sizes[0] / DIN;   // 100000
    const int E = in_sizes[5];         // 3200000
    float* out = (float*)d_out;

    char* base = (char*)d_ws;
    size_t o = 0;
    auto take = [&](size_t b) { size_t r = o; o += (b + 255) & ~(size_t)255; return r; };
    u32* outdeg8 = (u32*)(base + take((size_t)8 * N * 4));
    u32* cnt8    = (u32*)(base + take((size_t)8 * N * 4));
    size_t zero_bytes = o;   // zero the two privatized histograms
    int* indeg  = (int*)(base + take((size_t)N * 4));
    float* onorm = (float*)(base + take((size_t)N * 4));
    float* inorm = (float*)(base + take((size_t)N * 4));
    int* bsum = (int*)(base + take(256 * 4));
    int* bsex = (int*)(base + take(256 * 4));
    int* rp   = (int*)(base + take((size_t)(N + 1) * 4));
    u16* Wt1  = (u16*)(base + take((size_t)256 * 256 * 2));
    u16* Wt2  = (u16*)(base + take((size_t)64 * 256 * 2));
    u32* tag  = (u32*)(base + take((size_t)E * 4));
    int* es   = (int*)(base + take((size_t)E * 4));
    u16* S1   = (u16*)(base + take((size_t)N * 256 * 2));  // Xb, later B2
    u16* S2   = (u16*)(base + take((size_t)N * 256 * 2));  // A2
    u16* S3   = (u16*)(base + take((size_t)N * 64 * 2));   // Z
    (void)ws_size; (void)n_in; (void)out_size;

    u16* Xb = S1;
    u16* A2 = S2;
    u16* B2 = S1;
    u16* Z  = S3;

    hipMemsetAsync(base, 0, zero_bytes, stream);

    // CSR build, no device-scope atomics
    k_count<<<2048, 256, 0, stream>>>(src, dst, outdeg8, cnt8, tag, E, N);
    k_merge<<<(N + 255) / 256, 256, 0, stream>>>(outdeg8, cnt8, indeg, onorm, inorm, N);

    k_castx<<<8192, 256, 0, stream>>>(feat, onorm, Xb, N * 256);
    k_wt<<<(256 * 256 + 255) / 256, 256, 0, stream>>>(W1, Wt1, 256, 256);
    k_wt<<<(256 * 64 + 255) / 256, 256, 0, stream>>>(W2, Wt2, 256, 64);

    int CH = (N + NSB - 1) / NSB;   // 400
    k_scan_partial<<<NSB, 256, 0, stream>>>(indeg, bsum, N, CH);
    k_scan_top<<<1, 256, 0, stream>>>(bsum, bsex, rp, N);
    k_scan_write<<<NSB, 256, (size_t)CH * 4, stream>>>(indeg, bsex, rp, N, CH);
    dim3 grb((N + 255) / 256, 8);
    k_rpb<<<grb, 256, 0, stream>>>(cnt8, rp, N);
    k_place<<<2048, 256, 0, stream>>>(src, dst, tag, cnt8, es, E, N);

    int mtiles = (N + 127) / 128;

    // layer 1: A2 = grouped(Xb @ W1)
    dim3 g1(mtiles, 2);
    k_gemm<128, 2, 2, false, true><<<g1, 256, 0, stream>>>(Xb, Wt1, A2, N);
    k_spmm1<<<8192, 256, 0, stream>>>(A2, rp, es, inorm, onorm, b1, B2, N);

    // layer 2: Z = B2 @ W2 (plain [N][64])
    dim3 g2(mtiles, 1);
    k_gemm<64, 4, 1, true, false><<<g2, 256, 0, stream>>>(B2, Wt2, Z, N);
    k_spmm_out<<<8192, 256, 0, stream>>>(Z, rp, es, inorm, b2, out, N);
}